// Round 20
// baseline (105.811 us; speedup 1.0000x reference)
//
#include <hip/hip_runtime.h>
#include <hip/hip_bf16.h>

#define DH 32
#define BSZ 128      // nodes per bucket (v_local = 7 bits)
#define NBP 1024     // padded bucket count (N <= 131072 => B <= 1024)
#define SCAT_E 3840  // edges per scatter block
#define SCAT_P (2 * SCAT_E)
#define EPT 15       // edges per thread in scatter (SCAT_E/256)
#define PRE_E 8192   // edges per precount block
#define TS 4096      // pair codes per LDS tile in bmaxfin
#define PAD2 33      // aggL words per node (32 channels + 1 pad)

typedef short bf16x8 __attribute__((ext_vector_type(8)));
typedef float f32x4 __attribute__((ext_vector_type(4)));

__device__ __forceinline__ unsigned short f2bf(float x) {
    unsigned b = __float_as_uint(x);
    b += 0x7FFFu + ((b >> 16) & 1u);     // RNE
    return (unsigned short)(b >> 16);
}

// ---------------------------------------------------------------------------
// pre2: blocks [0, pgrid) = per-bucket endpoint histogram; block pgrid =
// weight preconversion to TRANSPOSED bf16 (Wt[c][k]) into wbf.
//   wbf layout: W1t [32][128] @0, W2t [32][32] @4096, Wft [32][32] @5120
// ---------------------------------------------------------------------------
__global__ __launch_bounds__(256) void pre2(
    const int* __restrict__ src, const int* __restrict__ dst,
    int* __restrict__ gtotal, int E, int pgrid,
    const float* __restrict__ W_in, const float* __restrict__ W_nbr,
    const float* __restrict__ W_ffnn, unsigned short* __restrict__ wbf)
{
    __shared__ int hist[NBP];
    const int tid = threadIdx.x;

    if ((int)blockIdx.x == pgrid) {
        for (int i = tid; i < 4096; i += 256) {
            int c = i >> 7, k = i & 127;
            wbf[i] = f2bf(W_in[k * 32 + c]);
        }
        for (int i = tid; i < 1024; i += 256) {
            int c = i >> 5, k = i & 31;
            wbf[4096 + i] = f2bf(W_nbr[k * 32 + c]);
            wbf[5120 + i] = f2bf(W_ffnn[k * 32 + c]);
        }
        return;
    }

    for (int i = tid; i < NBP; i += 256) hist[i] = 0;
    __syncthreads();
    const int e0 = blockIdx.x * PRE_E;
    const int eend = min(e0 + PRE_E, E);
    for (int e = e0 + tid; e < eend; e += 256) {
        atomicAdd(&hist[src[e] >> 7], 1);
        atomicAdd(&hist[dst[e] >> 7], 1);
    }
    __syncthreads();
    for (int i = tid; i < NBP; i += 256)
        if (hist[i] > 0) atomicAdd(&gtotal[i], hist[i]);
}

// ---------------------------------------------------------------------------
// Exclusive scan of gtotal[0..NBP) -> gbase; gcursor = gbase. One block.
// ---------------------------------------------------------------------------
__global__ __launch_bounds__(256) void scan_buckets(
    const int* __restrict__ gtotal, int* __restrict__ gbase,
    int* __restrict__ gcursor)
{
    __shared__ int ss[256];
    const int t = threadIdx.x;
    int v0 = gtotal[4 * t], v1 = gtotal[4 * t + 1];
    int v2 = gtotal[4 * t + 2], v3 = gtotal[4 * t + 3];
    int tsum = v0 + v1 + v2 + v3;
    ss[t] = tsum;
    __syncthreads();
    for (int off = 1; off < 256; off <<= 1) {
        int y = (t >= off) ? ss[t - off] : 0;
        __syncthreads();
        ss[t] += y;
        __syncthreads();
    }
    int e = ss[t] - tsum;
    gbase[4 * t] = e;                    gcursor[4 * t] = e;
    gbase[4 * t + 1] = e + v0;           gcursor[4 * t + 1] = e + v0;
    gbase[4 * t + 2] = e + v0 + v1;      gcursor[4 * t + 2] = e + v0 + v1;
    gbase[4 * t + 3] = e + v0 + v1 + v2; gcursor[4 * t + 3] = e + v0 + v1 + v2;
}

// ---------------------------------------------------------------------------
// FUSED scatproj: blocks [0, egrid) = bucket-granular scatter (38.9 KB LDS);
// blocks [egrid, egrid+jgrid) = MFMA node projection, 2 tiles/wave SOFTWARE
// PIPELINED: all 16 feat loads issued up front so both tiles' global-load
// latencies overlap (the old per-tile "memory"-clobbered waitcnt serialized
// them). u written node-major bf16 [N][32] into workspace.
// MFMA fragment layouts (m89-verified): A: row=l&15, k=(l>>4)*8+j;
// B: col=l&15, k=(l>>4)*8+j; C/D: col=l&15, row=(l>>4)*4+reg.
// ---------------------------------------------------------------------------
union SPSmem {
    struct {                                // 38.9 KB (scatter)
        unsigned code[SCAT_P];              // 30 KB
        int cur[NBP];                       // 4 KB (counts -> starts -> ends)
        int gbL[NBP];                       // 4 KB (also scan temp [0..3])
    } sc;
    struct {                                // 8 KB (proj)
        unsigned short htile[8][16 * 32];   // 2 per wave (pipelined bounce)
    } pj;
};

__global__ __launch_bounds__(256) void scatproj(
    const int* __restrict__ src, const int* __restrict__ dst,
    int* __restrict__ gcursor, unsigned* __restrict__ pairs_g,
    int E, int B, int egrid,
    const float* __restrict__ feat,
    const unsigned short* __restrict__ wbf,
    const float* __restrict__ b_in, const float* __restrict__ b_nbr,
    const float* __restrict__ b_n1, const float* __restrict__ b_ffnn,
    float* __restrict__ hpart, unsigned short* __restrict__ ub16,
    int N, int ntiles)
{
    __shared__ SPSmem sm;
    const int tid = threadIdx.x;

    if ((int)blockIdx.x < egrid) {
        // ================= scatter path =================
        const int e0 = blockIdx.x * SCAT_E;
        const int eend = min(e0 + SCAT_E, E);
        const int np = 2 * (eend - e0);

        for (int i = tid; i < NBP; i += 256) sm.sc.cur[i] = 0;
        __syncthreads();

        int es[EPT], dr[EPT];
#pragma unroll
        for (int j = 0; j < EPT; ++j) {
            int e = e0 + tid + j * 256;
            bool ok = (e < eend);
            es[j] = ok ? src[e] : -1;
            dr[j] = ok ? dst[e] : -1;
        }
#pragma unroll
        for (int j = 0; j < EPT; ++j) {
            if (es[j] >= 0) {
                atomicAdd(&sm.sc.cur[es[j] >> 7], 1);
                atomicAdd(&sm.sc.cur[dr[j] >> 7], 1);
            }
        }
        __syncthreads();

        // in-place exclusive scan of cur (counts -> starts); shfl-based
        {
            const int lane = tid & 63;
            const int w = tid >> 6;
            int v0 = sm.sc.cur[4 * tid], v1 = sm.sc.cur[4 * tid + 1];
            int v2 = sm.sc.cur[4 * tid + 2], v3 = sm.sc.cur[4 * tid + 3];
            int tsum = v0 + v1 + v2 + v3;
            int x = tsum;
#pragma unroll
            for (int off = 1; off < 64; off <<= 1) {
                int y = __shfl_up(x, off, 64);
                x += (lane >= off) ? y : 0;
            }
            if (lane == 63) sm.sc.gbL[w] = x;   // wave totals (temp use)
            __syncthreads();
            int woff = 0;
#pragma unroll
            for (int k = 0; k < 4; ++k) woff += (k < w) ? sm.sc.gbL[k] : 0;
            int ebase = woff + x - tsum;
            __syncthreads();                    // all reads of cur done
            sm.sc.cur[4 * tid] = ebase;
            sm.sc.cur[4 * tid + 1] = ebase + v0;
            sm.sc.cur[4 * tid + 2] = ebase + v0 + v1;
            sm.sc.cur[4 * tid + 3] = ebase + v0 + v1 + v2;
        }
        __syncthreads();

        // rank + reorder into LDS; bucket low byte in code[31:24]
#pragma unroll
        for (int j = 0; j < EPT; ++j) {
            if (es[j] >= 0) {
                int s = es[j], d = dr[j];
                int bs = s >> 7, bd = d >> 7;
                unsigned cs = ((unsigned)(bs & 255) << 24) |
                              ((unsigned)(s & 127) << 17) | (unsigned)d;
                unsigned cd = ((unsigned)(bd & 255) << 24) |
                              ((unsigned)(d & 127) << 17) | (unsigned)s;
                int p1 = atomicAdd(&sm.sc.cur[bs], 1);
                sm.sc.code[p1] = cs;
                int p2 = atomicAdd(&sm.sc.cur[bd], 1);
                sm.sc.code[p2] = cd;
            }
        }
        __syncthreads();
        // cur[b] = segment END; start(b) = cur[b-1] (segments packed)

        for (int b = tid; b < B; b += 256) {
            int end = sm.sc.cur[b];
            int start = b ? sm.sc.cur[b - 1] : 0;
            int c = end - start;
            if (c > 0) {
                int gw = atomicAdd(&gcursor[b], c);
                sm.sc.gbL[b] = gw - start;
            }
        }
        __syncthreads();

        // coalesced run writes; recover bucket via low byte + containment
        for (int i = tid; i < np; i += 256) {
            unsigned code = sm.sc.code[i];
            int cc = (int)(code >> 24);
#pragma unroll
            for (int k = 0; k < 3; ++k) {
                int hi2 = sm.sc.cur[cc];
                int lo2 = cc ? sm.sc.cur[cc - 1] : 0;
                bool in = (i < hi2) && (i >= lo2);
                cc = in ? cc : cc + 256;
            }
            pairs_g[sm.sc.gbL[cc] + i] = code & 0x00FFFFFFu;
        }
        return;
    }

    // ============ proj path (MFMA, 2 tiles/wave, pipelined) ============
    const int wid = tid >> 6, lane = tid & 63;
    const int r16 = lane & 15, kg = lane >> 4;
    const int w = ((int)blockIdx.x - egrid) * 4 + wid;
    const int t0i = w * 2;
    if (t0i >= ntiles) return;               // wave-uniform
    const bool tv1 = (t0i + 1 < ntiles);
    const int t1i = tv1 ? t0i + 1 : t0i;

    const unsigned short* W1t = wbf;         // [32][128]
    const unsigned short* W2t = wbf + 4096;  // [32][32]
    const unsigned short* Wft = wbf + 5120;  // [32][32]

    // B fragments: single 16B vector loads (preconverted, transposed)
    bf16x8 B1[4][2], B2[2], Bf[2];
#pragma unroll
    for (int ks = 0; ks < 4; ++ks)
#pragma unroll
        for (int ct = 0; ct < 2; ++ct)
            B1[ks][ct] = *(const bf16x8*)&W1t[(ct * 16 + r16) * 128 + ks * 32 + kg * 8];
#pragma unroll
    for (int ct = 0; ct < 2; ++ct) {
        B2[ct] = *(const bf16x8*)&W2t[(ct * 16 + r16) * 32 + kg * 8];
        Bf[ct] = *(const bf16x8*)&Wft[(ct * 16 + r16) * 32 + kg * 8];
    }

    const float b1a = b_in[r16],            b1b = b_in[16 + r16];
    const float b2a = b_nbr[r16] + b_n1[r16];
    const float b2b = b_nbr[16 + r16] + b_n1[16 + r16];
    const float bfa = b_ffnn[r16],          bfb = b_ffnn[16 + r16];

    const int tb0 = t0i * 16, tb1 = t1i * 16;
    const int nA0 = tb0 + r16, nA1 = tb1 + r16;
    const bool ok0 = (nA0 < N);
    const bool ok1 = tv1 && (nA1 < N);
    const float* fr0 = feat + (size_t)(ok0 ? nA0 : 0) * 128;
    const float* fr1 = feat + (size_t)(ok1 ? nA1 : 0) * 128;

    // issue ALL 16 feat loads up front (both tiles overlap in flight)
    const float4 z4 = make_float4(0.f, 0.f, 0.f, 0.f);
    float4 q0[8], q1[8];
#pragma unroll
    for (int ks = 0; ks < 4; ++ks) {
        q0[2 * ks]     = ok0 ? *(const float4*)(fr0 + ks * 32 + kg * 8)     : z4;
        q0[2 * ks + 1] = ok0 ? *(const float4*)(fr0 + ks * 32 + kg * 8 + 4) : z4;
        q1[2 * ks]     = ok1 ? *(const float4*)(fr1 + ks * 32 + kg * 8)     : z4;
        q1[2 * ks + 1] = ok1 ? *(const float4*)(fr1 + ks * 32 + kg * 8 + 4) : z4;
    }

    unsigned short* hl0 = &sm.pj.htile[wid * 2][0];
    unsigned short* hl1 = &sm.pj.htile[wid * 2 + 1][0];

    // --- tile0: convert + GEMM1 + LDS write (tile1 loads still in flight)
    {
        bf16x8 A[4];
#pragma unroll
        for (int ks = 0; ks < 4; ++ks) {
            float4 p0 = q0[2 * ks], p1 = q0[2 * ks + 1];
            A[ks][0] = (short)f2bf(p0.x); A[ks][1] = (short)f2bf(p0.y);
            A[ks][2] = (short)f2bf(p0.z); A[ks][3] = (short)f2bf(p0.w);
            A[ks][4] = (short)f2bf(p1.x); A[ks][5] = (short)f2bf(p1.y);
            A[ks][6] = (short)f2bf(p1.z); A[ks][7] = (short)f2bf(p1.w);
        }
        f32x4 acc0 = {b1a, b1a, b1a, b1a};
        f32x4 acc1 = {b1b, b1b, b1b, b1b};
#pragma unroll
        for (int ks = 0; ks < 4; ++ks) {
            acc0 = __builtin_amdgcn_mfma_f32_16x16x32_bf16(A[ks], B1[ks][0], acc0, 0, 0, 0);
            acc1 = __builtin_amdgcn_mfma_f32_16x16x32_bf16(A[ks], B1[ks][1], acc1, 0, 0, 0);
        }
#pragma unroll
        for (int r = 0; r < 4; ++r) {
            hl0[(kg * 4 + r) * 32 + r16]      = f2bf(acc0[r]);
            hl0[(kg * 4 + r) * 32 + 16 + r16] = f2bf(acc1[r]);
        }
    }

    // --- tile1: convert + GEMM1 + LDS write
    {
        bf16x8 A[4];
#pragma unroll
        for (int ks = 0; ks < 4; ++ks) {
            float4 p0 = q1[2 * ks], p1 = q1[2 * ks + 1];
            A[ks][0] = (short)f2bf(p0.x); A[ks][1] = (short)f2bf(p0.y);
            A[ks][2] = (short)f2bf(p0.z); A[ks][3] = (short)f2bf(p0.w);
            A[ks][4] = (short)f2bf(p1.x); A[ks][5] = (short)f2bf(p1.y);
            A[ks][6] = (short)f2bf(p1.z); A[ks][7] = (short)f2bf(p1.w);
        }
        f32x4 acc0 = {b1a, b1a, b1a, b1a};
        f32x4 acc1 = {b1b, b1b, b1b, b1b};
#pragma unroll
        for (int ks = 0; ks < 4; ++ks) {
            acc0 = __builtin_amdgcn_mfma_f32_16x16x32_bf16(A[ks], B1[ks][0], acc0, 0, 0, 0);
            acc1 = __builtin_amdgcn_mfma_f32_16x16x32_bf16(A[ks], B1[ks][1], acc1, 0, 0, 0);
        }
#pragma unroll
        for (int r = 0; r < 4; ++r) {
            hl1[(kg * 4 + r) * 32 + r16]      = f2bf(acc0[r]);
            hl1[(kg * 4 + r) * 32 + 16 + r16] = f2bf(acc1[r]);
        }
    }

    asm volatile("s_waitcnt lgkmcnt(0)" ::: "memory");
    bf16x8 A2_0 = *reinterpret_cast<const bf16x8*>(&hl0[r16 * 32 + kg * 8]);
    bf16x8 A2_1 = *reinterpret_cast<const bf16x8*>(&hl1[r16 * 32 + kg * 8]);

    // GEMM2 (u) and hpart for both tiles, K=32 single step each
    f32x4 u0_0 = {b2a, b2a, b2a, b2a}, u1_0 = {b2b, b2b, b2b, b2b};
    f32x4 u0_1 = {b2a, b2a, b2a, b2a}, u1_1 = {b2b, b2b, b2b, b2b};
    u0_0 = __builtin_amdgcn_mfma_f32_16x16x32_bf16(A2_0, B2[0], u0_0, 0, 0, 0);
    u1_0 = __builtin_amdgcn_mfma_f32_16x16x32_bf16(A2_0, B2[1], u1_0, 0, 0, 0);
    u0_1 = __builtin_amdgcn_mfma_f32_16x16x32_bf16(A2_1, B2[0], u0_1, 0, 0, 0);
    u1_1 = __builtin_amdgcn_mfma_f32_16x16x32_bf16(A2_1, B2[1], u1_1, 0, 0, 0);
    f32x4 g0_0 = {bfa, bfa, bfa, bfa}, g1_0 = {bfb, bfb, bfb, bfb};
    f32x4 g0_1 = {bfa, bfa, bfa, bfa}, g1_1 = {bfb, bfb, bfb, bfb};
    g0_0 = __builtin_amdgcn_mfma_f32_16x16x32_bf16(A2_0, Bf[0], g0_0, 0, 0, 0);
    g1_0 = __builtin_amdgcn_mfma_f32_16x16x32_bf16(A2_0, Bf[1], g1_0, 0, 0, 0);
    g0_1 = __builtin_amdgcn_mfma_f32_16x16x32_bf16(A2_1, Bf[0], g0_1, 0, 0, 0);
    g1_1 = __builtin_amdgcn_mfma_f32_16x16x32_bf16(A2_1, Bf[1], g1_1, 0, 0, 0);

    // stores: lane covers nodes tb + kg*4 + r, channels r16 / 16+r16
#pragma unroll
    for (int r = 0; r < 4; ++r) {
        const int n2 = tb0 + kg * 4 + r;
        if (n2 < N) {
            float s0 = 1.0f / (1.0f + __expf(-u0_0[r]));
            float s1 = 1.0f / (1.0f + __expf(-u1_0[r]));
            ub16[(size_t)n2 * 32 + r16]       = f2bf(s0);
            ub16[(size_t)n2 * 32 + 16 + r16]  = f2bf(s1);
            hpart[(size_t)n2 * 32 + r16]      = g0_0[r];
            hpart[(size_t)n2 * 32 + 16 + r16] = g1_0[r];
        }
    }
    if (tv1) {
#pragma unroll
        for (int r = 0; r < 4; ++r) {
            const int n2 = tb1 + kg * 4 + r;
            if (n2 < N) {
                float s0 = 1.0f / (1.0f + __expf(-u0_1[r]));
                float s1 = 1.0f / (1.0f + __expf(-u1_1[r]));
                ub16[(size_t)n2 * 32 + r16]       = f2bf(s0);
                ub16[(size_t)n2 * 32 + 16 + r16]  = f2bf(s1);
                hpart[(size_t)n2 * 32 + r16]      = g0_1[r];
                hpart[(size_t)n2 * 32 + 16 + r16] = g1_1[r];
            }
        }
    }
}

// ---------------------------------------------------------------------------
// bmaxfin: ONE 512-thread block per bucket. Max-aggregates all 32 channels
// into LDS (16-lane groups, 64B u-row gathers, 16-deep unroll), then computes
// out = hpart + agg @ W_ffnn[32:64] in-block (4 threads/node; aggL reads are
// conflict-free: bank (vl*33+k)%32 = (vl+k)%32).
// ---------------------------------------------------------------------------
__global__ __launch_bounds__(512) void bmaxfin(
    const unsigned* __restrict__ pairs_g, const int* __restrict__ gbase,
    const int* __restrict__ gtotal, const unsigned* __restrict__ ut32,
    const float* __restrict__ hpart, const float* __restrict__ W_ffnn,
    float* __restrict__ out, int N, int B)
{
    __shared__ unsigned aggL[BSZ * PAD2];  // 16.9 KB
    __shared__ int degL[BSZ];              // 0.5 KB
    __shared__ unsigned tile[TS];          // 16 KB
    __shared__ float sWf[1024];            // 4 KB (W_ffnn rows 32..63)

    const int tid = threadIdx.x;
    const int b = blockIdx.x;
    const int v0 = b * BSZ;

    for (int i = tid; i < BSZ * PAD2; i += 512) aggL[i] = 0u;
    for (int i = tid; i < BSZ; i += 512) degL[i] = 0;
    for (int i = tid; i < 1024; i += 512) sWf[i] = W_ffnn[1024 + i];
    __syncthreads();

    const int start = gbase[b];
    const int cnt = gtotal[b];
    const int gg = tid >> 4;       // 32 groups of 16 lanes
    const int cl = tid & 15;

    for (int t0 = 0; t0 < cnt; t0 += TS) {
        const int tn = min(TS, cnt - t0);
        for (int i = tid; i < tn; i += 512) tile[i] = pairs_g[start + t0 + i];
        __syncthreads();

        const int kmax = (tn - gg + 31) >> 5;   // <=0 if gg >= tn
        const int pm = tn - 1;
        for (int kk = 0; kk < kmax; kk += 16) {
            unsigned cc[16], xx[16];
#pragma unroll
            for (int u = 0; u < 16; ++u)
                cc[u] = tile[min(gg + (kk + u) * 32, pm)];
#pragma unroll
            for (int u = 0; u < 16; ++u)
                xx[u] = ut32[(size_t)(cc[u] & 0x1FFFF) * 16 + cl];
#pragma unroll
            for (int u = 0; u < 16; ++u) {
                atomicMax(&aggL[(cc[u] >> 17) * PAD2 + 2 * cl], (xx[u] & 0xFFFFu) << 16);
                atomicMax(&aggL[(cc[u] >> 17) * PAD2 + 2 * cl + 1], xx[u] & 0xFFFF0000u);
            }
            if (cl == 0) {
#pragma unroll
                for (int u = 0; u < 16; ++u)
                    if (gg + (kk + u) * 32 < tn) atomicAdd(&degL[cc[u] >> 17], 1);
            }
        }
        __syncthreads();
    }

    // fused FFN epilogue: 4 threads per node, 8 channels each
    const int vl = tid >> 2;           // 0..127
    const int c0 = (tid & 3) * 8;
    const int v = v0 + vl;
    if (v < N) {
        float acc[8];
        const float4* hr = (const float4*)(hpart + (size_t)v * 32 + c0);
        float4 h0 = hr[0], h1 = hr[1];
        acc[0] = h0.x; acc[1] = h0.y; acc[2] = h0.z; acc[3] = h0.w;
        acc[4] = h1.x; acc[5] = h1.y; acc[6] = h1.z; acc[7] = h1.w;
        if (degL[vl] > 1) {
#pragma unroll
            for (int k = 0; k < 32; ++k) {
                float av = __uint_as_float(aggL[vl * PAD2 + k]);
                const float* wr = &sWf[k * 32 + c0];
#pragma unroll
                for (int j = 0; j < 8; ++j)
                    acc[j] = fmaf(av, wr[j], acc[j]);
            }
        }
        float4* orow = (float4*)(out + (size_t)v * 32 + c0);
        orow[0] = make_float4(acc[0], acc[1], acc[2], acc[3]);
        orow[1] = make_float4(acc[4], acc[5], acc[6], acc[7]);
    }
}

// ---------------------------------------------------------------------------
extern "C" void kernel_launch(void* const* d_in, const int* in_sizes, int n_in,
                              void* d_out, int out_size, void* d_ws, size_t ws_size,
                              hipStream_t stream)
{
    const float* feat   = (const float*)d_in[0];
    const int*   src    = (const int*)d_in[1];
    const int*   dst    = (const int*)d_in[2];
    const float* W_in   = (const float*)d_in[3];
    const float* b_in   = (const float*)d_in[4];
    const float* W_nbr  = (const float*)d_in[5];
    const float* b_nbr  = (const float*)d_in[6];
    const float* b_n1   = (const float*)d_in[7];
    const float* W_ffnn = (const float*)d_in[8];
    const float* b_ffnn = (const float*)d_in[9];
    float* out = (float*)d_out;

    const int N = in_sizes[0] / 128;   // 100000 (N <= 131072 required by packing)
    const int E = in_sizes[1];
    const int B = (N + BSZ - 1) / BSZ; // 782 buckets (<= NBP)
    const int ntiles = (N + 15) / 16;  // 6250 16-node tiles

    // workspace layout (~27.2 MB, all in d_ws; out only written by bmaxfin)
    float* hpart   = (float*)d_ws;                        // N*32 f32  (12.8MB)
    unsigned short* ub16 = (unsigned short*)(hpart + (size_t)N * DH);  // N*32 bf16 (6.4MB)
    int*   gtotal  = (int*)(ub16 + (size_t)N * DH);       // NBP
    int*   gbase   = gtotal + NBP;                        // NBP
    int*   gcursor = gbase + NBP;                         // NBP
    unsigned* pairs_g = (unsigned*)(gcursor + NBP);       // 2E u32 (8MB)
    unsigned short* wbf = (unsigned short*)(pairs_g + 2 * (size_t)E);  // 6144 u16

    const int egrid = (E + SCAT_E - 1) / SCAT_E;          // 261
    const int pgrid = (E + PRE_E - 1) / PRE_E;            // 123
    const int jgrid = (ntiles + 7) / 8;                   // 782 proj blocks

    hipMemsetAsync(gtotal, 0, NBP * sizeof(int), stream);
    pre2<<<pgrid + 1, 256, 0, stream>>>(src, dst, gtotal, E, pgrid,
                                        W_in, W_nbr, W_ffnn, wbf);
    scan_buckets<<<1, 256, 0, stream>>>(gtotal, gbase, gcursor);
    scatproj<<<egrid + jgrid, 256, 0, stream>>>(
        src, dst, gcursor, pairs_g, E, B, egrid,
        feat, wbf, b_in, b_nbr, b_n1, b_ffnn,
        hpart, ub16, N, ntiles);
    bmaxfin<<<B, 512, 0, stream>>>(
        pairs_g, gbase, gtotal, (const unsigned*)ub16, hpart, W_ffnn,
        out, N, B);
}

// Round 21
// 90.635 us; speedup vs baseline: 1.1674x; 1.1674x over previous
//
#include <hip/hip_runtime.h>
#include <hip/hip_bf16.h>

#define DH 32
#define BSZ 128      // nodes per bucket (v_local = 7 bits)
#define NBP 1024     // padded bucket count (N <= 131072 => B <= 1024)
#define SCAT_E 3840  // edges per scatter block
#define SCAT_P (2 * SCAT_E)
#define EPT 15       // edges per thread in scatter (SCAT_E/256)
#define PRE_E 8192   // edges per precount block
#define TS 4096      // pair codes per LDS tile in bmaxfin
#define PAD2 33      // aggL words per node (32 channels + 1 pad)
#define TPW 2        // 16-node tiles per wave in proj

typedef short bf16x8 __attribute__((ext_vector_type(8)));
typedef float f32x4 __attribute__((ext_vector_type(4)));

__device__ __forceinline__ unsigned short f2bf(float x) {
    unsigned b = __float_as_uint(x);
    b += 0x7FFFu + ((b >> 16) & 1u);     // RNE
    return (unsigned short)(b >> 16);
}

// ---------------------------------------------------------------------------
// pre2: blocks [0, pgrid) = per-bucket endpoint histogram; block pgrid =
// weight preconversion to TRANSPOSED bf16 (Wt[c][k]) into wbf.
//   wbf layout: W1t [32][128] @0, W2t [32][32] @4096, Wft [32][32] @5120
// ---------------------------------------------------------------------------
__global__ __launch_bounds__(256) void pre2(
    const int* __restrict__ src, const int* __restrict__ dst,
    int* __restrict__ gtotal, int E, int pgrid,
    const float* __restrict__ W_in, const float* __restrict__ W_nbr,
    const float* __restrict__ W_ffnn, unsigned short* __restrict__ wbf)
{
    __shared__ int hist[NBP];
    const int tid = threadIdx.x;

    if ((int)blockIdx.x == pgrid) {
        for (int i = tid; i < 4096; i += 256) {
            int c = i >> 7, k = i & 127;
            wbf[i] = f2bf(W_in[k * 32 + c]);
        }
        for (int i = tid; i < 1024; i += 256) {
            int c = i >> 5, k = i & 31;
            wbf[4096 + i] = f2bf(W_nbr[k * 32 + c]);
            wbf[5120 + i] = f2bf(W_ffnn[k * 32 + c]);
        }
        return;
    }

    for (int i = tid; i < NBP; i += 256) hist[i] = 0;
    __syncthreads();
    const int e0 = blockIdx.x * PRE_E;
    const int eend = min(e0 + PRE_E, E);
    for (int e = e0 + tid; e < eend; e += 256) {
        atomicAdd(&hist[src[e] >> 7], 1);
        atomicAdd(&hist[dst[e] >> 7], 1);
    }
    __syncthreads();
    for (int i = tid; i < NBP; i += 256)
        if (hist[i] > 0) atomicAdd(&gtotal[i], hist[i]);
}

// ---------------------------------------------------------------------------
// Exclusive scan of gtotal[0..NBP) -> gbase; gcursor = gbase. One block.
// ---------------------------------------------------------------------------
__global__ __launch_bounds__(256) void scan_buckets(
    const int* __restrict__ gtotal, int* __restrict__ gbase,
    int* __restrict__ gcursor)
{
    __shared__ int ss[256];
    const int t = threadIdx.x;
    int v0 = gtotal[4 * t], v1 = gtotal[4 * t + 1];
    int v2 = gtotal[4 * t + 2], v3 = gtotal[4 * t + 3];
    int tsum = v0 + v1 + v2 + v3;
    ss[t] = tsum;
    __syncthreads();
    for (int off = 1; off < 256; off <<= 1) {
        int y = (t >= off) ? ss[t - off] : 0;
        __syncthreads();
        ss[t] += y;
        __syncthreads();
    }
    int e = ss[t] - tsum;
    gbase[4 * t] = e;                    gcursor[4 * t] = e;
    gbase[4 * t + 1] = e + v0;           gcursor[4 * t + 1] = e + v0;
    gbase[4 * t + 2] = e + v0 + v1;      gcursor[4 * t + 2] = e + v0 + v1;
    gbase[4 * t + 3] = e + v0 + v1 + v2; gcursor[4 * t + 3] = e + v0 + v1 + v2;
}

// ---------------------------------------------------------------------------
// FUSED scatproj: blocks [0, egrid) = bucket-granular scatter (38.9 KB LDS);
// blocks [egrid, egrid+jgrid) = MFMA node projection (TPW tiles/wave, wbf
// preconverted weights, 4 KB LDS). u is written NODE-MAJOR bf16 [N][32]
// into workspace (not d_out).
// MFMA fragment layouts (m89-verified): A: row=l&15, k=(l>>4)*8+j;
// B: col=l&15, k=(l>>4)*8+j; C/D: col=l&15, row=(l>>4)*4+reg.
// ---------------------------------------------------------------------------
union SPSmem {
    struct {                                // 38.9 KB (scatter)
        unsigned code[SCAT_P];              // 30 KB
        int cur[NBP];                       // 4 KB (counts -> starts -> ends)
        int gbL[NBP];                       // 4 KB (also scan temp [0..3])
    } sc;
    struct {                                // 4 KB (proj)
        unsigned short htile[4][16 * 32];   // per-wave h bounce
    } pj;
};

__global__ __launch_bounds__(256) void scatproj(
    const int* __restrict__ src, const int* __restrict__ dst,
    int* __restrict__ gcursor, unsigned* __restrict__ pairs_g,
    int E, int B, int egrid,
    const float* __restrict__ feat,
    const unsigned short* __restrict__ wbf,
    const float* __restrict__ b_in, const float* __restrict__ b_nbr,
    const float* __restrict__ b_n1, const float* __restrict__ b_ffnn,
    float* __restrict__ hpart, unsigned short* __restrict__ ub16,
    int N, int ntiles)
{
    __shared__ SPSmem sm;
    const int tid = threadIdx.x;

    if ((int)blockIdx.x < egrid) {
        // ================= scatter path =================
        const int e0 = blockIdx.x * SCAT_E;
        const int eend = min(e0 + SCAT_E, E);
        const int np = 2 * (eend - e0);

        for (int i = tid; i < NBP; i += 256) sm.sc.cur[i] = 0;
        __syncthreads();

        int es[EPT], dr[EPT];
#pragma unroll
        for (int j = 0; j < EPT; ++j) {
            int e = e0 + tid + j * 256;
            bool ok = (e < eend);
            es[j] = ok ? src[e] : -1;
            dr[j] = ok ? dst[e] : -1;
        }
#pragma unroll
        for (int j = 0; j < EPT; ++j) {
            if (es[j] >= 0) {
                atomicAdd(&sm.sc.cur[es[j] >> 7], 1);
                atomicAdd(&sm.sc.cur[dr[j] >> 7], 1);
            }
        }
        __syncthreads();

        // in-place exclusive scan of cur (counts -> starts); shfl-based
        {
            const int lane = tid & 63;
            const int w = tid >> 6;
            int v0 = sm.sc.cur[4 * tid], v1 = sm.sc.cur[4 * tid + 1];
            int v2 = sm.sc.cur[4 * tid + 2], v3 = sm.sc.cur[4 * tid + 3];
            int tsum = v0 + v1 + v2 + v3;
            int x = tsum;
#pragma unroll
            for (int off = 1; off < 64; off <<= 1) {
                int y = __shfl_up(x, off, 64);
                x += (lane >= off) ? y : 0;
            }
            if (lane == 63) sm.sc.gbL[w] = x;   // wave totals (temp use)
            __syncthreads();
            int woff = 0;
#pragma unroll
            for (int k = 0; k < 4; ++k) woff += (k < w) ? sm.sc.gbL[k] : 0;
            int ebase = woff + x - tsum;
            __syncthreads();                    // all reads of cur done
            sm.sc.cur[4 * tid] = ebase;
            sm.sc.cur[4 * tid + 1] = ebase + v0;
            sm.sc.cur[4 * tid + 2] = ebase + v0 + v1;
            sm.sc.cur[4 * tid + 3] = ebase + v0 + v1 + v2;
        }
        __syncthreads();

        // rank + reorder into LDS; bucket low byte in code[31:24]
#pragma unroll
        for (int j = 0; j < EPT; ++j) {
            if (es[j] >= 0) {
                int s = es[j], d = dr[j];
                int bs = s >> 7, bd = d >> 7;
                unsigned cs = ((unsigned)(bs & 255) << 24) |
                              ((unsigned)(s & 127) << 17) | (unsigned)d;
                unsigned cd = ((unsigned)(bd & 255) << 24) |
                              ((unsigned)(d & 127) << 17) | (unsigned)s;
                int p1 = atomicAdd(&sm.sc.cur[bs], 1);
                sm.sc.code[p1] = cs;
                int p2 = atomicAdd(&sm.sc.cur[bd], 1);
                sm.sc.code[p2] = cd;
            }
        }
        __syncthreads();
        // cur[b] = segment END; start(b) = cur[b-1] (segments packed)

        for (int b = tid; b < B; b += 256) {
            int end = sm.sc.cur[b];
            int start = b ? sm.sc.cur[b - 1] : 0;
            int c = end - start;
            if (c > 0) {
                int gw = atomicAdd(&gcursor[b], c);
                sm.sc.gbL[b] = gw - start;
            }
        }
        __syncthreads();

        // coalesced run writes; recover bucket via low byte + containment
        for (int i = tid; i < np; i += 256) {
            unsigned code = sm.sc.code[i];
            int cc = (int)(code >> 24);
#pragma unroll
            for (int k = 0; k < 3; ++k) {
                int hi2 = sm.sc.cur[cc];
                int lo2 = cc ? sm.sc.cur[cc - 1] : 0;
                bool in = (i < hi2) && (i >= lo2);
                cc = in ? cc : cc + 256;
            }
            pairs_g[sm.sc.gbL[cc] + i] = code & 0x00FFFFFFu;
        }
        return;
    }

    // ================= proj path (MFMA, TPW tiles/wave) =================
    const int wid = tid >> 6, lane = tid & 63;
    const int r16 = lane & 15, kg = lane >> 4;
    const int w = ((int)blockIdx.x - egrid) * 4 + wid;
    const int t0 = w * TPW;
    if (t0 >= ntiles) return;                // wave-uniform

    const unsigned short* W1t = wbf;         // [32][128]
    const unsigned short* W2t = wbf + 4096;  // [32][32]
    const unsigned short* Wft = wbf + 5120;  // [32][32]

    // B fragments: single 16B vector loads (preconverted, transposed)
    bf16x8 B1[4][2], B2[2], Bf[2];
#pragma unroll
    for (int ks = 0; ks < 4; ++ks)
#pragma unroll
        for (int ct = 0; ct < 2; ++ct)
            B1[ks][ct] = *(const bf16x8*)&W1t[(ct * 16 + r16) * 128 + ks * 32 + kg * 8];
#pragma unroll
    for (int ct = 0; ct < 2; ++ct) {
        B2[ct] = *(const bf16x8*)&W2t[(ct * 16 + r16) * 32 + kg * 8];
        Bf[ct] = *(const bf16x8*)&Wft[(ct * 16 + r16) * 32 + kg * 8];
    }

    const float b1a = b_in[r16],            b1b = b_in[16 + r16];
    const float b2a = b_nbr[r16] + b_n1[r16];
    const float b2b = b_nbr[16 + r16] + b_n1[16 + r16];
    const float bfa = b_ffnn[r16],          bfb = b_ffnn[16 + r16];

    unsigned short* hl = &sm.pj.htile[wid][0];

#pragma unroll
    for (int i = 0; i < TPW; ++i) {
        const int ti = t0 + i;
        const bool tv = (ti < ntiles);
        const int t = tv ? ti : ntiles - 1;
        const int tbase = t * 16;
        const int nA = tbase + r16;
        const bool okA = tv && (nA < N);
        const float* fr = feat + (size_t)(okA ? nA : 0) * 128;

        // A fragments: 8 consecutive k per lane (two float4 loads + cvt)
        bf16x8 A[4];
#pragma unroll
        for (int ks = 0; ks < 4; ++ks) {
            float4 p0 = make_float4(0.f, 0.f, 0.f, 0.f);
            float4 p1 = make_float4(0.f, 0.f, 0.f, 0.f);
            if (okA) {
                p0 = *(const float4*)(fr + ks * 32 + kg * 8);
                p1 = *(const float4*)(fr + ks * 32 + kg * 8 + 4);
            }
            A[ks][0] = (short)f2bf(p0.x); A[ks][1] = (short)f2bf(p0.y);
            A[ks][2] = (short)f2bf(p0.z); A[ks][3] = (short)f2bf(p0.w);
            A[ks][4] = (short)f2bf(p1.x); A[ks][5] = (short)f2bf(p1.y);
            A[ks][6] = (short)f2bf(p1.z); A[ks][7] = (short)f2bf(p1.w);
        }

        // GEMM1: h-tile = feat-tile @ W_in + b_in
        f32x4 acc0 = {b1a, b1a, b1a, b1a};
        f32x4 acc1 = {b1b, b1b, b1b, b1b};
#pragma unroll
        for (int ks = 0; ks < 4; ++ks) {
            acc0 = __builtin_amdgcn_mfma_f32_16x16x32_bf16(A[ks], B1[ks][0], acc0, 0, 0, 0);
            acc1 = __builtin_amdgcn_mfma_f32_16x16x32_bf16(A[ks], B1[ks][1], acc1, 0, 0, 0);
        }

        // bounce h (bf16) through wave-private LDS: C-layout -> A-layout
#pragma unroll
        for (int r = 0; r < 4; ++r) {
            hl[(kg * 4 + r) * 32 + r16]      = f2bf(acc0[r]);
            hl[(kg * 4 + r) * 32 + 16 + r16] = f2bf(acc1[r]);
        }
        asm volatile("s_waitcnt lgkmcnt(0)" ::: "memory");
        bf16x8 A2 = *reinterpret_cast<const bf16x8*>(&hl[r16 * 32 + kg * 8]);

        // GEMM2 (u) and hpart, K=32 single step each
        f32x4 u0 = {b2a, b2a, b2a, b2a};
        f32x4 u1 = {b2b, b2b, b2b, b2b};
        u0 = __builtin_amdgcn_mfma_f32_16x16x32_bf16(A2, B2[0], u0, 0, 0, 0);
        u1 = __builtin_amdgcn_mfma_f32_16x16x32_bf16(A2, B2[1], u1, 0, 0, 0);
        f32x4 g0 = {bfa, bfa, bfa, bfa};
        f32x4 g1 = {bfb, bfb, bfb, bfb};
        g0 = __builtin_amdgcn_mfma_f32_16x16x32_bf16(A2, Bf[0], g0, 0, 0, 0);
        g1 = __builtin_amdgcn_mfma_f32_16x16x32_bf16(A2, Bf[1], g1, 0, 0, 0);

        // stores: lane covers nodes tbase + kg*4 + r, channel r16 (+16);
        // u is node-major [N][32] bf16 in workspace
#pragma unroll
        for (int r = 0; r < 4; ++r) {
            const int n2 = tbase + kg * 4 + r;
            if (tv && n2 < N) {
                float s0 = 1.0f / (1.0f + __expf(-u0[r]));
                float s1 = 1.0f / (1.0f + __expf(-u1[r]));
                ub16[(size_t)n2 * 32 + r16]       = f2bf(s0);
                ub16[(size_t)n2 * 32 + 16 + r16]  = f2bf(s1);
                hpart[(size_t)n2 * 32 + r16]      = g0[r];
                hpart[(size_t)n2 * 32 + 16 + r16] = g1[r];
            }
        }
    }
}

// ---------------------------------------------------------------------------
// bmaxfin: ONE 512-thread block per bucket. Max-aggregates all 32 channels
// into LDS (16-lane groups, 64B u-row gathers, 16-deep unroll), then computes
// out = hpart + agg @ W_ffnn[32:64] in-block (4 threads/node; aggL reads are
// conflict-free: bank (vl*33+k)%32 = (vl+k)%32).
// ---------------------------------------------------------------------------
__global__ __launch_bounds__(512) void bmaxfin(
    const unsigned* __restrict__ pairs_g, const int* __restrict__ gbase,
    const int* __restrict__ gtotal, const unsigned* __restrict__ ut32,
    const float* __restrict__ hpart, const float* __restrict__ W_ffnn,
    float* __restrict__ out, int N, int B)
{
    __shared__ unsigned aggL[BSZ * PAD2];  // 16.9 KB
    __shared__ int degL[BSZ];              // 0.5 KB
    __shared__ unsigned tile[TS];          // 16 KB
    __shared__ float sWf[1024];            // 4 KB (W_ffnn rows 32..63)

    const int tid = threadIdx.x;
    const int b = blockIdx.x;
    const int v0 = b * BSZ;

    for (int i = tid; i < BSZ * PAD2; i += 512) aggL[i] = 0u;
    for (int i = tid; i < BSZ; i += 512) degL[i] = 0;
    for (int i = tid; i < 1024; i += 512) sWf[i] = W_ffnn[1024 + i];
    __syncthreads();

    const int start = gbase[b];
    const int cnt = gtotal[b];
    const int gg = tid >> 4;       // 32 groups of 16 lanes
    const int cl = tid & 15;

    for (int t0 = 0; t0 < cnt; t0 += TS) {
        const int tn = min(TS, cnt - t0);
        for (int i = tid; i < tn; i += 512) tile[i] = pairs_g[start + t0 + i];
        __syncthreads();

        const int kmax = (tn - gg + 31) >> 5;   // <=0 if gg >= tn
        const int pm = tn - 1;
        for (int kk = 0; kk < kmax; kk += 16) {
            unsigned cc[16], xx[16];
#pragma unroll
            for (int u = 0; u < 16; ++u)
                cc[u] = tile[min(gg + (kk + u) * 32, pm)];
#pragma unroll
            for (int u = 0; u < 16; ++u)
                xx[u] = ut32[(size_t)(cc[u] & 0x1FFFF) * 16 + cl];
#pragma unroll
            for (int u = 0; u < 16; ++u) {
                atomicMax(&aggL[(cc[u] >> 17) * PAD2 + 2 * cl], (xx[u] & 0xFFFFu) << 16);
                atomicMax(&aggL[(cc[u] >> 17) * PAD2 + 2 * cl + 1], xx[u] & 0xFFFF0000u);
            }
            if (cl == 0) {
#pragma unroll
                for (int u = 0; u < 16; ++u)
                    if (gg + (kk + u) * 32 < tn) atomicAdd(&degL[cc[u] >> 17], 1);
            }
        }
        __syncthreads();
    }

    // fused FFN epilogue: 4 threads per node, 8 channels each
    const int vl = tid >> 2;           // 0..127
    const int c0 = (tid & 3) * 8;
    const int v = v0 + vl;
    if (v < N) {
        float acc[8];
        const float4* hr = (const float4*)(hpart + (size_t)v * 32 + c0);
        float4 h0 = hr[0], h1 = hr[1];
        acc[0] = h0.x; acc[1] = h0.y; acc[2] = h0.z; acc[3] = h0.w;
        acc[4] = h1.x; acc[5] = h1.y; acc[6] = h1.z; acc[7] = h1.w;
        if (degL[vl] > 1) {
#pragma unroll
            for (int k = 0; k < 32; ++k) {
                float av = __uint_as_float(aggL[vl * PAD2 + k]);
                const float* wr = &sWf[k * 32 + c0];
#pragma unroll
                for (int j = 0; j < 8; ++j)
                    acc[j] = fmaf(av, wr[j], acc[j]);
            }
        }
        float4* orow = (float4*)(out + (size_t)v * 32 + c0);
        orow[0] = make_float4(acc[0], acc[1], acc[2], acc[3]);
        orow[1] = make_float4(acc[4], acc[5], acc[6], acc[7]);
    }
}

// ---------------------------------------------------------------------------
extern "C" void kernel_launch(void* const* d_in, const int* in_sizes, int n_in,
                              void* d_out, int out_size, void* d_ws, size_t ws_size,
                              hipStream_t stream)
{
    const float* feat   = (const float*)d_in[0];
    const int*   src    = (const int*)d_in[1];
    const int*   dst    = (const int*)d_in[2];
    const float* W_in   = (const float*)d_in[3];
    const float* b_in   = (const float*)d_in[4];
    const float* W_nbr  = (const float*)d_in[5];
    const float* b_nbr  = (const float*)d_in[6];
    const float* b_n1   = (const float*)d_in[7];
    const float* W_ffnn = (const float*)d_in[8];
    const float* b_ffnn = (const float*)d_in[9];
    float* out = (float*)d_out;

    const int N = in_sizes[0] / 128;   // 100000 (N <= 131072 required by packing)
    const int E = in_sizes[1];
    const int B = (N + BSZ - 1) / BSZ; // 782 buckets (<= NBP)
    const int ntiles = (N + 15) / 16;  // 6250 16-node tiles

    // workspace layout (~27.2 MB, all in d_ws; out only written by bmaxfin)
    float* hpart   = (float*)d_ws;                        // N*32 f32  (12.8MB)
    unsigned short* ub16 = (unsigned short*)(hpart + (size_t)N * DH);  // N*32 bf16 (6.4MB)
    int*   gtotal  = (int*)(ub16 + (size_t)N * DH);       // NBP
    int*   gbase   = gtotal + NBP;                        // NBP
    int*   gcursor = gbase + NBP;                         // NBP
    unsigned* pairs_g = (unsigned*)(gcursor + NBP);       // 2E u32 (8MB)
    unsigned short* wbf = (unsigned short*)(pairs_g + 2 * (size_t)E);  // 6144 u16

    const int egrid = (E + SCAT_E - 1) / SCAT_E;          // 261
    const int pgrid = (E + PRE_E - 1) / PRE_E;            // 123
    const int jgrid = (ntiles + 4 * TPW - 1) / (4 * TPW); // 782 proj blocks

    hipMemsetAsync(gtotal, 0, NBP * sizeof(int), stream);
    pre2<<<pgrid + 1, 256, 0, stream>>>(src, dst, gtotal, E, pgrid,
                                        W_in, W_nbr, W_ffnn, wbf);
    scan_buckets<<<1, 256, 0, stream>>>(gtotal, gbase, gcursor);
    scatproj<<<egrid + jgrid, 256, 0, stream>>>(
        src, dst, gcursor, pairs_g, E, B, egrid,
        feat, wbf, b_in, b_nbr, b_n1, b_ffnn,
        hpart, ub16, N, ntiles);
    bmaxfin<<<B, 512, 0, stream>>>(
        pairs_g, gbase, gtotal, (const unsigned*)ub16, hpart, W_ffnn,
        out, N, B);
}